// Round 1
// baseline (179.750 us; speedup 1.0000x reference)
//
#include <hip/hip_runtime.h>
#include <cmath>

// Problem constants (from reference setup_inputs)
constexpr int kB = 32;   // batch
constexpr int kA = 3;    // anchors
constexpr int kH = 64;
constexpr int kW = 64;
constexpr int kC = 85;
constexpr int kN = 64;   // targets per sample
constexpr int kCells = kA * kH * kW;          // 12288
constexpr int kChunks = 16;                   // blocks per sample
constexpr int kCellsPerChunk = kCells / kChunks; // 768
constexpr int kBlock = 256;
constexpr float kThreshold = 0.5f;
constexpr float kNoObjW = 0.5f;

__global__ __launch_bounds__(kBlock) void objloss_kernel(
    const float* __restrict__ output,   // (B,A,H,W,C) f32
    const float* __restrict__ targets,  // (B,N,5) f32
    const float* __restrict__ anchors,  // (A,2) f32
    float* __restrict__ out)            // scalar, pre-zeroed
{
    __shared__ unsigned int bitmap[kCells / 32]; // 384 words = full gt mask for this sample
    __shared__ float red[kBlock / 64];

    const int blk   = blockIdx.x;
    const int b     = blk / kChunks;
    const int chunk = blk % kChunks;
    const int tid   = threadIdx.x;

    // zero LDS bitmap
    for (int i = tid; i < kCells / 32; i += kBlock) bitmap[i] = 0u;
    __syncthreads();

    // Phase 1: one thread per target, mark gt cells (redundant per chunk, but trivial)
    if (tid < kN) {
        const float* t = targets + ((size_t)b * kN + tid) * 5;
        float x = t[1], y = t[2], w = t[3], h = t[4];
        bool valid = !(x == 0.0f && y == 0.0f && w == 0.0f && h == 0.0f);

        float tx = x * kW, ty = y * kH, tw = w * kW, th = h * kH;
        float cx = floorf(tx), cy = floorf(ty);
        float zx = tx - (cx + 0.5f), zy = ty - (cy + 0.5f);

        float t_x0 = zx - tw * 0.5f, t_y0 = zy - th * 0.5f;
        float t_x1 = zx + tw * 0.5f, t_y1 = zy + th * 0.5f;
        float area_t = tw * th;

        float best = -1.0f;
        int aidx = 0;
        #pragma unroll
        for (int a = 0; a < kA; ++a) {
            float aw = anchors[a * 2 + 0], ah = anchors[a * 2 + 1];
            float x0 = fmaxf(t_x0, -aw * 0.5f);
            float y0 = fmaxf(t_y0, -ah * 0.5f);
            float x1 = fminf(t_x1,  aw * 0.5f);
            float y1 = fminf(t_y1,  ah * 0.5f);
            float inter = ((x0 < x1) && (y0 < y1)) ? (x1 - x0) * (y1 - y0) : 0.0f;
            float iou = inter / (area_t + aw * ah - inter);
            if (iou > best) { best = iou; aidx = a; }  // first-max wins (matches jnp.argmax)
        }
        if (valid && best > kThreshold) {
            int cxi = min(max((int)cx, 0), kW - 1);
            int cyi = min(max((int)cy, 0), kH - 1);
            int cell = aidx * (kH * kW) + cyi * kW + cxi;
            atomicOr(&bitmap[cell >> 5], 1u << (cell & 31));
        }
    }
    __syncthreads();

    // Phase 2: scan this chunk's cells of the objectness channel
    const float* p_base = output + (size_t)b * kCells * kC + 4;
    float acc = 0.0f;
    #pragma unroll
    for (int j = 0; j < kCellsPerChunk / kBlock; ++j) {
        int cell = chunk * kCellsPerChunk + j * kBlock + tid;
        float p = p_base[(size_t)cell * kC];
        bool gt = (bitmap[cell >> 5] >> (cell & 31)) & 1u;
        float lp  = fmaxf(logf(p),     -100.0f);
        float l1p = fmaxf(log1pf(-p),  -100.0f);
        acc += gt ? -lp : -kNoObjW * l1p;
    }

    // Wave reduction (wave64)
    #pragma unroll
    for (int off = 32; off > 0; off >>= 1)
        acc += __shfl_down(acc, off, 64);
    if ((tid & 63) == 0) red[tid >> 6] = acc;
    __syncthreads();
    if (tid == 0) {
        float s = 0.0f;
        #pragma unroll
        for (int i = 0; i < kBlock / 64; ++i) s += red[i];
        atomicAdd(out, s * (1.0f / ((float)kCells * (float)kB)));
    }
}

extern "C" void kernel_launch(void* const* d_in, const int* in_sizes, int n_in,
                              void* d_out, int out_size, void* d_ws, size_t ws_size,
                              hipStream_t stream) {
    const float* output  = (const float*)d_in[0];
    const float* targets = (const float*)d_in[1];
    const float* anchors = (const float*)d_in[2];
    float* out = (float*)d_out;

    // d_out is re-poisoned to 0xAA before every call — zero it (async memset is capture-safe)
    hipMemsetAsync(d_out, 0, sizeof(float), stream);

    objloss_kernel<<<dim3(kB * kChunks), dim3(kBlock), 0, stream>>>(output, targets, anchors, out);
}

// Round 2
// 178.436 us; speedup vs baseline: 1.0074x; 1.0074x over previous
//
#include <hip/hip_runtime.h>
#include <cmath>

// Problem constants (from reference setup_inputs)
constexpr int kB = 32;   // batch
constexpr int kA = 3;    // anchors
constexpr int kH = 64;
constexpr int kW = 64;
constexpr int kC = 85;
constexpr int kN = 64;   // targets per sample
constexpr int kCells = kA * kH * kW;          // 12288 cells per sample
constexpr int kWords = kCells / 32;           // 384 bitmap words per sample
constexpr int kBlock = 256;
constexpr int kBlocksPerSample = kCells / kBlock; // 48
constexpr int kGridMain = kB * kBlocksPerSample;  // 1536
constexpr float kThreshold = 0.5f;
constexpr float kNoObjW = 0.5f;

// d_ws layout:
//   [0, kB*kWords)                     : uint32 gt bitmaps (one per sample)
//   [kB*kWords, kB*kWords + kGridMain) : float per-block partial sums

// ---------------------------------------------------------------------------
// Kernel 1: build gt bitmaps. One block per sample, 64 threads (one/target).
// ---------------------------------------------------------------------------
__global__ __launch_bounds__(64) void mark_kernel(
    const float* __restrict__ targets,  // (B,N,5)
    const float* __restrict__ anchors,  // (A,2)
    unsigned int* __restrict__ bitmaps) // (B, kWords)
{
    __shared__ unsigned int bm[kWords];
    const int b   = blockIdx.x;
    const int tid = threadIdx.x;

    #pragma unroll
    for (int i = tid; i < kWords; i += 64) bm[i] = 0u;
    __syncthreads();

    {
        const float* t = targets + ((size_t)b * kN + tid) * 5;
        float x = t[1], y = t[2], w = t[3], h = t[4];
        bool valid = !(x == 0.0f && y == 0.0f && w == 0.0f && h == 0.0f);

        float tx = x * kW, ty = y * kH, tw = w * kW, th = h * kH;
        float cx = floorf(tx), cy = floorf(ty);
        float zx = tx - (cx + 0.5f), zy = ty - (cy + 0.5f);

        float t_x0 = zx - tw * 0.5f, t_y0 = zy - th * 0.5f;
        float t_x1 = zx + tw * 0.5f, t_y1 = zy + th * 0.5f;
        float area_t = tw * th;

        float best = -1.0f;
        int aidx = 0;
        #pragma unroll
        for (int a = 0; a < kA; ++a) {
            float aw = anchors[a * 2 + 0], ah = anchors[a * 2 + 1];
            float x0 = fmaxf(t_x0, -aw * 0.5f);
            float y0 = fmaxf(t_y0, -ah * 0.5f);
            float x1 = fminf(t_x1,  aw * 0.5f);
            float y1 = fminf(t_y1,  ah * 0.5f);
            float inter = ((x0 < x1) && (y0 < y1)) ? (x1 - x0) * (y1 - y0) : 0.0f;
            float iou = inter / (area_t + aw * ah - inter);
            if (iou > best) { best = iou; aidx = a; }  // first-max wins (jnp.argmax)
        }
        if (valid && best > kThreshold) {
            int cxi = min(max((int)cx, 0), kW - 1);
            int cyi = min(max((int)cy, 0), kH - 1);
            int cell = aidx * (kH * kW) + cyi * kW + cxi;
            atomicOr(&bm[cell >> 5], 1u << (cell & 31));
        }
    }
    __syncthreads();

    // plain stores overwrite poison — no pre-zeroing of d_ws needed
    #pragma unroll
    for (int i = tid; i < kWords; i += 64)
        bitmaps[(size_t)b * kWords + i] = bm[i];
}

// ---------------------------------------------------------------------------
// Kernel 2: main scan. 1 cell per thread, 1536 blocks. Partial per block.
// ---------------------------------------------------------------------------
__global__ __launch_bounds__(kBlock) void scan_kernel(
    const float* __restrict__ output,           // (B,A,H,W,C)
    const unsigned int* __restrict__ bitmaps,   // (B, kWords), L2-hot (48 KB)
    float* __restrict__ partials)               // (kGridMain)
{
    __shared__ float red[kBlock / 64];

    const int blk  = blockIdx.x;
    const int b    = blk / kBlocksPerSample;
    const int cell = (blk % kBlocksPerSample) * kBlock + threadIdx.x;
    const int tid  = threadIdx.x;

    float p = output[(size_t)b * kCells * kC + (size_t)cell * kC + 4];
    unsigned int w = bitmaps[(size_t)b * kWords + (cell >> 5)];
    bool gt = (w >> (cell & 31)) & 1u;

    float lp  = fmaxf(logf(p),    -100.0f);
    float l1p = fmaxf(log1pf(-p), -100.0f);
    float acc = gt ? -lp : -kNoObjW * l1p;

    #pragma unroll
    for (int off = 32; off > 0; off >>= 1)
        acc += __shfl_down(acc, off, 64);
    if ((tid & 63) == 0) red[tid >> 6] = acc;
    __syncthreads();
    if (tid == 0) {
        float s = 0.0f;
        #pragma unroll
        for (int i = 0; i < kBlock / 64; ++i) s += red[i];
        partials[blk] = s;  // plain store, overwrites poison
    }
}

// ---------------------------------------------------------------------------
// Kernel 3: reduce 1536 partials -> scalar loss. One block.
// ---------------------------------------------------------------------------
__global__ __launch_bounds__(kBlock) void reduce_kernel(
    const float* __restrict__ partials,
    float* __restrict__ out)
{
    __shared__ float red[kBlock / 64];
    const int tid = threadIdx.x;

    float acc = 0.0f;
    #pragma unroll
    for (int i = 0; i < kGridMain / kBlock; ++i)   // 6 each
        acc += partials[i * kBlock + tid];

    #pragma unroll
    for (int off = 32; off > 0; off >>= 1)
        acc += __shfl_down(acc, off, 64);
    if ((tid & 63) == 0) red[tid >> 6] = acc;
    __syncthreads();
    if (tid == 0) {
        float s = 0.0f;
        #pragma unroll
        for (int i = 0; i < kBlock / 64; ++i) s += red[i];
        out[0] = s * (1.0f / ((float)kCells * (float)kB));  // plain store
    }
}

extern "C" void kernel_launch(void* const* d_in, const int* in_sizes, int n_in,
                              void* d_out, int out_size, void* d_ws, size_t ws_size,
                              hipStream_t stream) {
    const float* output  = (const float*)d_in[0];
    const float* targets = (const float*)d_in[1];
    const float* anchors = (const float*)d_in[2];
    float* out = (float*)d_out;

    unsigned int* bitmaps = (unsigned int*)d_ws;
    float* partials = (float*)((unsigned int*)d_ws + (size_t)kB * kWords);

    mark_kernel<<<dim3(kB), dim3(64), 0, stream>>>(targets, anchors, bitmaps);
    scan_kernel<<<dim3(kGridMain), dim3(kBlock), 0, stream>>>(output, bitmaps, partials);
    reduce_kernel<<<dim3(1), dim3(kBlock), 0, stream>>>(partials, out);
}